// Round 11
// baseline (418.842 us; speedup 1.0000x reference)
//
#include <hip/hip_runtime.h>

typedef float f32x4 __attribute__((ext_vector_type(4)));
typedef short s16x8 __attribute__((ext_vector_type(8)));
typedef unsigned int u32;
typedef u32 u32x4 __attribute__((ext_vector_type(4)));
typedef unsigned long long u64;
typedef unsigned short ush;

#define CD    256
#define NB    64
#define NBETA 512
#define NHID  512
#define PPB   32    // positions per fused block

__device__ __forceinline__ ush f2bf(float x) {
    u32 u = __builtin_bit_cast(u32, x);
    u += 0x7fffu + ((u >> 16) & 1u);
    return (ush)(u >> 16);
}
__device__ __forceinline__ float bf2f(ush h) {
    u32 u = ((u32)h) << 16;
    return __builtin_bit_cast(float, u);
}
__device__ __forceinline__ float bflo(u32 u) {
    return __builtin_bit_cast(float, u << 16);
}
__device__ __forceinline__ float bfhi(u32 u) {
    return __builtin_bit_cast(float, u & 0xFFFF0000u);
}
__device__ __forceinline__ u32 cvtpk(float lo, float hi) {
    u32 r;
    asm("v_cvt_pk_bf16_f32 %0, %1, %2" : "=v"(r) : "v"(lo), "v"(hi));
    return r;
}
__device__ __forceinline__ float fexp2(float x) {  // 2^x
    float r;
    asm("v_exp_f32 %0, %1" : "=v"(r) : "v"(x));
    return r;
}

// ---------------------------------------------------------------------------
// Prep (unchanged, proven): hws[b][beta] bf16; wwb = bf16(W_w).
// ---------------------------------------------------------------------------
__global__ __launch_bounds__(512) void prep_kernel(
    const float* __restrict__ h_t, const float* __restrict__ W_h_w,
    const float* __restrict__ W_h_b, const float* __restrict__ W_w,
    const float* __restrict__ W_b,
    ush* __restrict__ hws, ush* __restrict__ wwb)
{
    const int blk = blockIdx.x;
    const int tid = threadIdx.x;
    if (blk < NB) {
        __shared__ float hrow[NHID];
        hrow[tid] = h_t[blk * NHID + tid];
        __syncthreads();
        const float* wr = W_h_w + tid * NHID;
        float a0 = 0.f, a1 = 0.f, a2 = 0.f, a3 = 0.f;
        #pragma unroll 4
        for (int h = 0; h < NHID; h += 4) {
            f32x4 wv = *(const f32x4*)(wr + h);
            a0 = fmaf(wv.x, hrow[h], a0);
            a1 = fmaf(wv.y, hrow[h + 1], a1);
            a2 = fmaf(wv.z, hrow[h + 2], a2);
            a3 = fmaf(wv.w, hrow[h + 3], a3);
        }
        float acc = (a0 + a1) + (a2 + a3) + W_h_b[tid] + W_b[tid];
        hws[blk * NBETA + tid] = f2bf(acc);   // [b][beta]
    } else {
        const int idx = ((blk - NB) * 512 + tid) * 8;
        f32x4 a = *(const f32x4*)(W_w + idx);
        f32x4 b = *(const f32x4*)(W_w + idx + 4);
        s16x8 pk;
        pk[0] = (short)f2bf(a.x); pk[1] = (short)f2bf(a.y);
        pk[2] = (short)f2bf(a.z); pk[3] = (short)f2bf(a.w);
        pk[4] = (short)f2bf(b.x); pk[5] = (short)f2bf(b.y);
        pk[6] = (short)f2bf(b.z); pk[7] = (short)f2bf(b.w);
        *(s16x8*)(wwb + idx) = pk;
    }
}

// ---------------------------------------------------------------------------
// Fused: 1024 thr = 16 waves x 32 betas (all 512), block = (b-half, 32 pos).
// vs round 10: A-frags a[2][8]=64 regs -> ~130/lane -> 4 waves/SIMD (2x TLP);
// keeps round-10 mechanics: full-range swizzle (conflict-free), wsum from
// retained pk regs at TOP (zero post-barrier LDS V read), prefetch dist 2,
// 3-buffer Vt, ONE barrier/position. No setprio, single load clump.
// ---------------------------------------------------------------------------
__global__ __launch_bounds__(1024) void fused(
    const float* __restrict__ V,
    const ush* __restrict__ wwb,
    const ush* __restrict__ hws,
    const float* __restrict__ beta_w,
    const float* __restrict__ beta_b,
    float* __restrict__ num,
    float* __restrict__ lsum)
{
    __shared__ __align__(16) char VtB[3][16384];   // [32 b][256 c] bf16 swz
    __shared__ float nbS[NBETA];                   // -2*beta_w
    __shared__ __align__(16) float ew2[2][32][20]; // [parity][b][wave], pad 20

    const int tid = threadIdx.x;
    const int l = tid & 63, w = tid >> 6, g = l >> 4, r = l & 15;
    const int bl = tid & 31, cs = tid >> 5;        // b-lane, c-slice of 8
    const int bh = blockIdx.x & 1, chunk = blockIdx.x >> 1;

    if (tid < NBETA) nbS[tid] = -2.f * beta_w[tid];
    const float bbias = beta_b[0];

    // base = sum of this lane's 8 bw values (position-invariant)
    float base;
    {
        f32x4 t0 = *(const f32x4*)(beta_w + w * 32 + g * 4);
        f32x4 t1 = *(const f32x4*)(beta_w + w * 32 + 16 + g * 4);
        base = (t0.x + t0.y) + (t0.z + t0.w) + (t1.x + t1.y) + (t1.z + t1.w);
    }

    // permanent A fragments: beta = w*32 + m*16 + r  (64 VGPR)
    const ush* wbase = wwb + (size_t)(w * 32 + r) * CD + g * 8;
    s16x8 a[2][8];
    #pragma unroll
    for (int m = 0; m < 2; ++m)
        #pragma unroll
        for (int ks = 0; ks < 8; ++ks)
            a[m][ks] = *(const s16x8*)(wbase + m * (16 * CD) + ks * 32);

    // permanent hterm: ua[m][n] = betas (w*32+m*16+g*4..+3) at b=bh*32+n*16+r
    const ush* hbase = hws + (size_t)(bh * 32 + r) * NBETA + w * 32 + g * 4;
    u64 ua[2][2];
    #pragma unroll
    for (int m = 0; m < 2; ++m)
        #pragma unroll
        for (int n = 0; n < 2; ++n)
            ua[m][n] = *(const u64*)(hbase + n * (16 * NBETA) + m * 16);

    const int p0 = chunk * PPB;
    const float* vbase = V + (size_t)p0 * (CD * NB) + bh * 32 + bl;
    const int wswz = (bl & 15) << 4;
    const int rswz = r << 4;

    float cacc[8];
    #pragma unroll
    for (int j = 0; j < 8; ++j) cacc[j] = 0.f;
    float lacc = 0.f;

    float nv[8];
    u32x4 pkA, pkB;

    // prologue: load pos0 -> pack pkB -> stage buf0; issue pos1 loads
    {
        #pragma unroll
        for (int j = 0; j < 8; ++j)
            nv[j] = __builtin_nontemporal_load(vbase + (cs * 8 + j) * NB);
        pkB = (u32x4){cvtpk(nv[0], nv[1]), cvtpk(nv[2], nv[3]),
                      cvtpk(nv[4], nv[5]), cvtpk(nv[6], nv[7])};
        *(u32x4*)(VtB[0] + bl * 512 + ((cs * 16) ^ wswz)) = pkB;
        const float* vp = vbase + (size_t)(CD * NB);
        #pragma unroll
        for (int j = 0; j < 8; ++j)
            nv[j] = __builtin_nontemporal_load(vp + (cs * 8 + j) * NB);
    }
    __syncthreads();

#define WSUM(PK, EP)                                                          \
    {                                                                         \
        const float* er = &ew2[EP][bl][0];                                    \
        f32x4 s0 = *(const f32x4*)er;                                         \
        f32x4 s1 = *(const f32x4*)(er + 4);                                   \
        f32x4 s2 = *(const f32x4*)(er + 8);                                   \
        f32x4 s3 = *(const f32x4*)(er + 12);                                  \
        f32x4 s4 = (s0 + s1) + (s2 + s3);                                     \
        float e = bbias + (s4.x + s4.y) + (s4.z + s4.w);                      \
        float wgt = __expf(e);                                                \
        lacc += wgt;                                                          \
        _Pragma("unroll")                                                     \
        for (int w2 = 0; w2 < 4; ++w2) {                                      \
            u32 u = PK[w2];                                                   \
            cacc[w2 * 2]     = fmaf(wgt, bflo(u), cacc[w2 * 2]);              \
            cacc[w2 * 2 + 1] = fmaf(wgt, bfhi(u), cacc[w2 * 2 + 1]);          \
        }                                                                     \
    }

#define BODY(I, PK, EC, EP)                                                   \
    {                                                                         \
        const int i_ = (I);                                                   \
        if (i_ > 0) WSUM(PK, EP)                                              \
        if (i_ + 1 < PPB) {                                                   \
            PK = (u32x4){cvtpk(nv[0], nv[1]), cvtpk(nv[2], nv[3]),            \
                         cvtpk(nv[4], nv[5]), cvtpk(nv[6], nv[7])};           \
            *(u32x4*)(VtB[0] + off_w + bl * 512 + ((cs * 16) ^ wswz)) = PK;   \
        }                                                                     \
        if (i_ + 2 < PPB) {                                                   \
            const float* vp = vbase + (size_t)(i_ + 2) * (CD * NB);           \
            _Pragma("unroll")                                                 \
            for (int j = 0; j < 8; ++j)                                       \
                nv[j] = __builtin_nontemporal_load(vp + (cs * 8 + j) * NB);   \
        }                                                                     \
        const char* vrow = VtB[0] + off_r + r * 512;                          \
        f32x4 acc0[2], acc1[2];                                               \
        _Pragma("unroll")                                                     \
        for (int m = 0; m < 2; ++m) {                                         \
            u64 h0 = ua[m][0], h1 = ua[m][1];                                 \
            acc0[m] = (f32x4){bf2f((ush)h0), bf2f((ush)(h0 >> 16)),           \
                              bf2f((ush)(h0 >> 32)), bf2f((ush)(h0 >> 48))};  \
            acc1[m] = (f32x4){bf2f((ush)h1), bf2f((ush)(h1 >> 16)),           \
                              bf2f((ush)(h1 >> 32)), bf2f((ush)(h1 >> 48))};  \
        }                                                                     \
        _Pragma("unroll")                                                     \
        for (int ks = 0; ks < 8; ++ks) {                                      \
            const int off = ((ks << 6) | (g << 4)) ^ rswz;                    \
            s16x8 b0 = *(const s16x8*)(vrow + off);                           \
            s16x8 b1 = *(const s16x8*)(vrow + 8192 + off);                    \
            _Pragma("unroll")                                                 \
            for (int m = 0; m < 2; ++m) {                                     \
                acc0[m] = __builtin_amdgcn_mfma_f32_16x16x32_bf16(            \
                    a[m][ks], b0, acc0[m], 0, 0, 0);                          \
                acc1[m] = __builtin_amdgcn_mfma_f32_16x16x32_bf16(            \
                    a[m][ks], b1, acc1[m], 0, 0, 0);                          \
            }                                                                 \
        }                                                                     \
        float pe0 = base, pe1 = base;                                         \
        _Pragma("unroll")                                                     \
        for (int m = 0; m < 2; ++m) {                                         \
            f32x4 nbv = *(const f32x4*)(&nbS[w * 32 + m * 16 + g * 4]);       \
            _Pragma("unroll")                                                 \
            for (int q = 0; q < 4; ++q) {                                     \
                float s0 = __builtin_amdgcn_rcpf(                             \
                    1.f + fexp2(acc0[m][q] * 2.8853900817779268f));           \
                float s1 = __builtin_amdgcn_rcpf(                             \
                    1.f + fexp2(acc1[m][q] * 2.8853900817779268f));           \
                pe0 = fmaf(nbv[q], s0, pe0);                                  \
                pe1 = fmaf(nbv[q], s1, pe1);                                  \
            }                                                                 \
        }                                                                     \
        pe0 += __shfl_xor(pe0, 16, 64); pe0 += __shfl_xor(pe0, 32, 64);       \
        pe1 += __shfl_xor(pe1, 16, 64); pe1 += __shfl_xor(pe1, 32, 64);       \
        if (l < 16) { ew2[EC][l][w] = pe0; ew2[EC][16 + l][w] = pe1; }        \
        __syncthreads();                                                      \
        off_r = off_w;                                                        \
        off_w += 16384; if (off_w == 49152) off_w = 0;                        \
    }

    int off_r = 0, off_w = 16384;
    for (int ii = 0; ii < PPB; ii += 2) {
        BODY(ii,     pkA, 0, 1)
        BODY(ii + 1, pkB, 1, 0)
    }
    // final wsum: pos PPB-1 (packed in BODY(PPB-2) -> pkA), ew parity 1
    WSUM(pkA, 1)

#undef BODY
#undef WSUM

    float* np = num + (size_t)blockIdx.x * (32 * CD) + bl * CD + cs * 8;
    *(f32x4*)(np)     = (f32x4){cacc[0], cacc[1], cacc[2], cacc[3]};
    *(f32x4*)(np + 4) = (f32x4){cacc[4], cacc[5], cacc[6], cacc[7]};
    if (cs == 0) lsum[blockIdx.x * 32 + bl] = lacc;
}

// ---------------------------------------------------------------------------
// Combine (unchanged): 256 blocks = (b 64 x cq 4); 256 thr = (cl 64 x kq 4).
// ---------------------------------------------------------------------------
__global__ __launch_bounds__(256) void combine4(
    const float* __restrict__ num, const float* __restrict__ lsum,
    float* __restrict__ out)
{
    __shared__ float rs[4][64];
    __shared__ float rl[4][64];
    const int b = blockIdx.x >> 2, cq = blockIdx.x & 3;
    const int bh = b >> 5, blr = b & 31;
    const int cl = threadIdx.x & 63, kq = threadIdx.x >> 6;

    float s = 0.f, ls = 0.f;
    #pragma unroll 4
    for (int ch = kq * 32; ch < kq * 32 + 32; ++ch) {
        const int blk = ch * 2 + bh;
        s += num[(size_t)blk * (32 * CD) + blr * CD + cq * 64 + cl];
        ls += lsum[blk * 32 + blr];
    }
    rs[kq][cl] = s; rl[kq][cl] = ls;
    __syncthreads();
    if (kq == 0) {
        float sn = rs[0][cl] + rs[1][cl] + rs[2][cl] + rs[3][cl];
        float sl = rl[0][cl] + rl[1][cl] + rl[2][cl] + rl[3][cl];
        out[b * CD + cq * 64 + cl] = sn / sl;
    }
}

extern "C" void kernel_launch(void* const* d_in, const int* in_sizes, int n_in,
                              void* d_out, int out_size, void* d_ws, size_t ws_size,
                              hipStream_t stream)
{
    (void)in_sizes; (void)n_in; (void)out_size; (void)ws_size;
    const float* V      = (const float*)d_in[0];
    const float* h_t    = (const float*)d_in[1];
    const float* W_h_w  = (const float*)d_in[2];
    const float* W_h_b  = (const float*)d_in[3];
    const float* W_w    = (const float*)d_in[4];
    const float* W_b    = (const float*)d_in[5];
    const float* beta_w = (const float*)d_in[6];
    const float* beta_b = (const float*)d_in[7];

    char* ws = (char*)d_ws;
    ush*   wwb = (ush*)ws;                                   // 256 KB
    ush*   hws = (ush*)(ws + 262144);                        // 64 KB
    float* num = (float*)(ws + 262144 + 65536);              // 8.4 MB
    float* lsm = (float*)(ws + 262144 + 65536 + 8388608);    // 32 KB

    hipLaunchKernelGGL(prep_kernel, dim3(96), dim3(512), 0, stream,
                       h_t, W_h_w, W_h_b, W_w, W_b, hws, wwb);
    hipLaunchKernelGGL(fused, dim3(256), dim3(1024), 0, stream,
                       V, wwb, hws, beta_w, beta_b, num, lsm);
    hipLaunchKernelGGL(combine4, dim3(256), dim3(256), 0, stream,
                       num, lsm, (float*)d_out);
}

// Round 12
// 155.220 us; speedup vs baseline: 2.6984x; 2.6984x over previous
//
#include <hip/hip_runtime.h>

typedef float f32x4 __attribute__((ext_vector_type(4)));
typedef short s16x8 __attribute__((ext_vector_type(8)));
typedef unsigned int u32;
typedef u32 u32x4 __attribute__((ext_vector_type(4)));
typedef unsigned long long u64;
typedef unsigned short ush;

#define CD    256
#define NB    64
#define NBETA 512
#define NHID  512
#define PPB   32    // positions per fused block

__device__ __forceinline__ ush f2bf(float x) {
    u32 u = __builtin_bit_cast(u32, x);
    u += 0x7fffu + ((u >> 16) & 1u);
    return (ush)(u >> 16);
}
__device__ __forceinline__ float bf2f(ush h) {
    u32 u = ((u32)h) << 16;
    return __builtin_bit_cast(float, u);
}
__device__ __forceinline__ u32 cvtpk(float lo, float hi) {
    u32 r;
    asm("v_cvt_pk_bf16_f32 %0, %1, %2" : "=v"(r) : "v"(lo), "v"(hi));
    return r;
}
__device__ __forceinline__ float fexp2(float x) {  // 2^x
    float r;
    asm("v_exp_f32 %0, %1" : "=v"(r) : "v"(x));
    return r;
}

// ---------------------------------------------------------------------------
// Prep (unchanged, proven): hws[b][beta] bf16; wwb = bf16(W_w).
// ---------------------------------------------------------------------------
__global__ __launch_bounds__(512) void prep_kernel(
    const float* __restrict__ h_t, const float* __restrict__ W_h_w,
    const float* __restrict__ W_h_b, const float* __restrict__ W_w,
    const float* __restrict__ W_b,
    ush* __restrict__ hws, ush* __restrict__ wwb)
{
    const int blk = blockIdx.x;
    const int tid = threadIdx.x;
    if (blk < NB) {
        __shared__ float hrow[NHID];
        hrow[tid] = h_t[blk * NHID + tid];
        __syncthreads();
        const float* wr = W_h_w + tid * NHID;
        float a0 = 0.f, a1 = 0.f, a2 = 0.f, a3 = 0.f;
        #pragma unroll 4
        for (int h = 0; h < NHID; h += 4) {
            f32x4 wv = *(const f32x4*)(wr + h);
            a0 = fmaf(wv.x, hrow[h], a0);
            a1 = fmaf(wv.y, hrow[h + 1], a1);
            a2 = fmaf(wv.z, hrow[h + 2], a2);
            a3 = fmaf(wv.w, hrow[h + 3], a3);
        }
        float acc = (a0 + a1) + (a2 + a3) + W_h_b[tid] + W_b[tid];
        hws[blk * NBETA + tid] = f2bf(acc);   // [b][beta]
    } else {
        const int idx = ((blk - NB) * 512 + tid) * 8;
        f32x4 a = *(const f32x4*)(W_w + idx);
        f32x4 b = *(const f32x4*)(W_w + idx + 4);
        s16x8 pk;
        pk[0] = (short)f2bf(a.x); pk[1] = (short)f2bf(a.y);
        pk[2] = (short)f2bf(a.z); pk[3] = (short)f2bf(a.w);
        pk[4] = (short)f2bf(b.x); pk[5] = (short)f2bf(b.y);
        pk[6] = (short)f2bf(b.z); pk[7] = (short)f2bf(b.w);
        *(s16x8*)(wwb + idx) = pk;
    }
}

// ---------------------------------------------------------------------------
// Fused: 1024 thr = 16 waves x 32 betas (all 512), block = (b-half, 32 pos).
// Round-12 = round-9's PROVEN mechanics (sequential n-chains, 3-buffer,
// wsum-from-LDS post-barrier, one barrier/pos, prefetch dist 2) at 2x the
// waves/CU (16 vs 8), with a strict <=128-reg diet:
//   a[2][8]=64, ua=8, nv=8, cacc=8, ONE reused acc[2]=8, no retained pk.
// (Round-11 lesson: interleaved acc chains + retained pk = 132 regs = spill.)
// ---------------------------------------------------------------------------
__global__ __launch_bounds__(1024) void fused(
    const float* __restrict__ V,
    const ush* __restrict__ wwb,
    const ush* __restrict__ hws,
    const float* __restrict__ beta_w,
    const float* __restrict__ beta_b,
    float* __restrict__ num,
    float* __restrict__ lsum)
{
    __shared__ __align__(16) char VtB[3][16384];   // [32 b][256 c] bf16 swz
    __shared__ float nbS[NBETA];                   // -2*beta_w
    __shared__ __align__(16) float ew2[2][32][20]; // [parity][b][wave], pad 20

    const int tid = threadIdx.x;
    const int l = tid & 63, w = tid >> 6, g = l >> 4, r = l & 15;
    const int bl = tid & 31, cs = tid >> 5;        // b-lane, c-slice of 8
    const int bh = blockIdx.x & 1, chunk = blockIdx.x >> 1;

    if (tid < NBETA) nbS[tid] = -2.f * beta_w[tid];
    const float bbias = beta_b[0];

    // base = sum of this lane's 8 bw values (position-invariant)
    float base;
    {
        f32x4 t0 = *(const f32x4*)(beta_w + w * 32 + g * 4);
        f32x4 t1 = *(const f32x4*)(beta_w + w * 32 + 16 + g * 4);
        base = (t0.x + t0.y) + (t0.z + t0.w) + (t1.x + t1.y) + (t1.z + t1.w);
    }

    // permanent A fragments: beta = w*32 + m*16 + r  (64 VGPR)
    const ush* wbase = wwb + (size_t)(w * 32 + r) * CD + g * 8;
    s16x8 a[2][8];
    #pragma unroll
    for (int m = 0; m < 2; ++m)
        #pragma unroll
        for (int ks = 0; ks < 8; ++ks)
            a[m][ks] = *(const s16x8*)(wbase + m * (16 * CD) + ks * 32);

    // permanent hterm: ua[m][n] = betas (w*32+m*16+g*4..+3) at b=bh*32+n*16+r
    const ush* hbase = hws + (size_t)(bh * 32 + r) * NBETA + w * 32 + g * 4;
    u64 ua[2][2];
    #pragma unroll
    for (int m = 0; m < 2; ++m)
        #pragma unroll
        for (int n = 0; n < 2; ++n)
            ua[m][n] = *(const u64*)(hbase + n * (16 * NBETA) + m * 16);

    const int p0 = chunk * PPB;
    const float* vbase = V + (size_t)p0 * (CD * NB) + bh * 32 + bl;
    const int wswz = (bl & 15) << 4;
    const int rswz = r << 4;

    float cacc[8];
    #pragma unroll
    for (int j = 0; j < 8; ++j) cacc[j] = 0.f;
    float lacc = 0.f;

    float nv[8];

    // prologue: load pos0 -> stage buf0; issue pos1 loads into nv
    {
        #pragma unroll
        for (int j = 0; j < 8; ++j)
            nv[j] = __builtin_nontemporal_load(vbase + (cs * 8 + j) * NB);
        u32x4 pk = {cvtpk(nv[0], nv[1]), cvtpk(nv[2], nv[3]),
                    cvtpk(nv[4], nv[5]), cvtpk(nv[6], nv[7])};
        *(u32x4*)(VtB[0] + bl * 512 + ((cs * 16) ^ wswz)) = pk;
        const float* vp = vbase + (size_t)(CD * NB);
        #pragma unroll
        for (int j = 0; j < 8; ++j)
            nv[j] = __builtin_nontemporal_load(vp + (cs * 8 + j) * NB);
    }
    __syncthreads();

    int off_r = 0, off_w = 16384;
    for (int i = 0; i < PPB; ++i) {
        // (1) stage pos i+1 (loads issued LAST iteration -> latency hidden)
        if (i + 1 < PPB) {
            u32x4 pk = {cvtpk(nv[0], nv[1]), cvtpk(nv[2], nv[3]),
                        cvtpk(nv[4], nv[5]), cvtpk(nv[6], nv[7])};
            *(u32x4*)(VtB[0] + off_w + bl * 512 + ((cs * 16) ^ wswz)) = pk;
        }
        // (2) issue pos i+2 loads
        if (i + 2 < PPB) {
            const float* vp = vbase + (size_t)(i + 2) * (CD * NB);
            #pragma unroll
            for (int j = 0; j < 8; ++j)
                nv[j] = __builtin_nontemporal_load(vp + (cs * 8 + j) * NB);
        }

        const char* vrow = VtB[0] + off_r + r * 512;

        // (3) n=0: init from ua, K-chain, epilogue (ONE reused acc[2])
        float pe0, pe1;
        {
            f32x4 acc[2];
            #pragma unroll
            for (int m = 0; m < 2; ++m) {
                u64 h = ua[m][0];
                acc[m] = (f32x4){bf2f((ush)h), bf2f((ush)(h >> 16)),
                                 bf2f((ush)(h >> 32)), bf2f((ush)(h >> 48))};
            }
            #pragma unroll
            for (int ks = 0; ks < 8; ++ks) {
                const int off = ((ks << 6) | (g << 4)) ^ rswz;
                s16x8 b0 = *(const s16x8*)(vrow + off);
                #pragma unroll
                for (int m = 0; m < 2; ++m)
                    acc[m] = __builtin_amdgcn_mfma_f32_16x16x32_bf16(
                        a[m][ks], b0, acc[m], 0, 0, 0);
            }
            pe0 = base;
            #pragma unroll
            for (int m = 0; m < 2; ++m) {
                f32x4 nbv = *(const f32x4*)(&nbS[w * 32 + m * 16 + g * 4]);
                #pragma unroll
                for (int q = 0; q < 4; ++q) {
                    float s = __builtin_amdgcn_rcpf(
                        1.f + fexp2(acc[m][q] * 2.8853900817779268f));
                    pe0 = fmaf(nbv[q], s, pe0);
                }
            }
        }
        // (4) n=1: same, reusing the register set
        {
            f32x4 acc[2];
            #pragma unroll
            for (int m = 0; m < 2; ++m) {
                u64 h = ua[m][1];
                acc[m] = (f32x4){bf2f((ush)h), bf2f((ush)(h >> 16)),
                                 bf2f((ush)(h >> 32)), bf2f((ush)(h >> 48))};
            }
            #pragma unroll
            for (int ks = 0; ks < 8; ++ks) {
                const int off = ((ks << 6) | (g << 4)) ^ rswz;
                s16x8 b1 = *(const s16x8*)(vrow + 8192 + off);
                #pragma unroll
                for (int m = 0; m < 2; ++m)
                    acc[m] = __builtin_amdgcn_mfma_f32_16x16x32_bf16(
                        a[m][ks], b1, acc[m], 0, 0, 0);
            }
            pe1 = base;
            #pragma unroll
            for (int m = 0; m < 2; ++m) {
                f32x4 nbv = *(const f32x4*)(&nbS[w * 32 + m * 16 + g * 4]);
                #pragma unroll
                for (int q = 0; q < 4; ++q) {
                    float s = __builtin_amdgcn_rcpf(
                        1.f + fexp2(acc[m][q] * 2.8853900817779268f));
                    pe1 = fmaf(nbv[q], s, pe1);
                }
            }
        }

        // (5) cross-lane reduce (over g) + partial store
        pe0 += __shfl_xor(pe0, 16, 64); pe0 += __shfl_xor(pe0, 32, 64);
        pe1 += __shfl_xor(pe1, 16, 64); pe1 += __shfl_xor(pe1, 32, 64);
        if (l < 16) { ew2[i & 1][l][w] = pe0; ew2[i & 1][16 + l][w] = pe1; }

        __syncthreads();   // the ONLY barrier per position

        // (6) e-sum + wsum from the staged tile (paired adds, low transients)
        {
            const float* er = &ew2[i & 1][bl][0];
            f32x4 sA = *(const f32x4*)er + *(const f32x4*)(er + 4);
            f32x4 sB = *(const f32x4*)(er + 8) + *(const f32x4*)(er + 12);
            f32x4 s4 = sA + sB;
            float e = bbias + (s4.x + s4.y) + (s4.z + s4.w);
            float wgt = __expf(e);
            lacc += wgt;
            s16x8 v = *(const s16x8*)(VtB[0] + off_r + bl * 512 + ((cs * 16) ^ wswz));
            #pragma unroll
            for (int j = 0; j < 8; ++j)
                cacc[j] = fmaf(wgt, bf2f((ush)v[j]), cacc[j]);
        }

        off_r = off_w;
        off_w += 16384;
        if (off_w == 49152) off_w = 0;
    }

    // partials: num[block][32 b][256 c]
    float* np = num + (size_t)blockIdx.x * (32 * CD) + bl * CD + cs * 8;
    *(f32x4*)(np)     = (f32x4){cacc[0], cacc[1], cacc[2], cacc[3]};
    *(f32x4*)(np + 4) = (f32x4){cacc[4], cacc[5], cacc[6], cacc[7]};
    if (cs == 0) lsum[blockIdx.x * 32 + bl] = lacc;
}

// ---------------------------------------------------------------------------
// Combine (unchanged): 256 blocks = (b 64 x cq 4); 256 thr = (cl 64 x kq 4).
// ---------------------------------------------------------------------------
__global__ __launch_bounds__(256) void combine4(
    const float* __restrict__ num, const float* __restrict__ lsum,
    float* __restrict__ out)
{
    __shared__ float rs[4][64];
    __shared__ float rl[4][64];
    const int b = blockIdx.x >> 2, cq = blockIdx.x & 3;
    const int bh = b >> 5, blr = b & 31;
    const int cl = threadIdx.x & 63, kq = threadIdx.x >> 6;

    float s = 0.f, ls = 0.f;
    #pragma unroll 4
    for (int ch = kq * 32; ch < kq * 32 + 32; ++ch) {
        const int blk = ch * 2 + bh;
        s += num[(size_t)blk * (32 * CD) + blr * CD + cq * 64 + cl];
        ls += lsum[blk * 32 + blr];
    }
    rs[kq][cl] = s; rl[kq][cl] = ls;
    __syncthreads();
    if (kq == 0) {
        float sn = rs[0][cl] + rs[1][cl] + rs[2][cl] + rs[3][cl];
        float sl = rl[0][cl] + rl[1][cl] + rl[2][cl] + rl[3][cl];
        out[b * CD + cq * 64 + cl] = sn / sl;
    }
}

extern "C" void kernel_launch(void* const* d_in, const int* in_sizes, int n_in,
                              void* d_out, int out_size, void* d_ws, size_t ws_size,
                              hipStream_t stream)
{
    (void)in_sizes; (void)n_in; (void)out_size; (void)ws_size;
    const float* V      = (const float*)d_in[0];
    const float* h_t    = (const float*)d_in[1];
    const float* W_h_w  = (const float*)d_in[2];
    const float* W_h_b  = (const float*)d_in[3];
    const float* W_w    = (const float*)d_in[4];
    const float* W_b    = (const float*)d_in[5];
    const float* beta_w = (const float*)d_in[6];
    const float* beta_b = (const float*)d_in[7];

    char* ws = (char*)d_ws;
    ush*   wwb = (ush*)ws;                                   // 256 KB
    ush*   hws = (ush*)(ws + 262144);                        // 64 KB
    float* num = (float*)(ws + 262144 + 65536);              // 8.4 MB
    float* lsm = (float*)(ws + 262144 + 65536 + 8388608);    // 32 KB

    hipLaunchKernelGGL(prep_kernel, dim3(96), dim3(512), 0, stream,
                       h_t, W_h_w, W_h_b, W_w, W_b, hws, wwb);
    hipLaunchKernelGGL(fused, dim3(256), dim3(1024), 0, stream,
                       V, wwb, hws, beta_w, beta_b, num, lsm);
    hipLaunchKernelGGL(combine4, dim3(256), dim3(256), 0, stream,
                       num, lsm, (float*)d_out);
}